// Round 1
// baseline (765.178 us; speedup 1.0000x reference)
//
#include <hip/hip_runtime.h>

typedef unsigned short u16;
typedef __attribute__((ext_vector_type(4))) float f32x4;
typedef __bf16 bf16x8 __attribute__((ext_vector_type(8)));

#define DI __device__ __forceinline__

DI u16 f2bf(float f) {
  unsigned u = __builtin_bit_cast(unsigned, f);
  u += 0x7fffu + ((u >> 16) & 1u);
  return (u16)(u >> 16);
}
DI float bf2f(u16 h) {
  unsigned u = ((unsigned)h) << 16;
  return __builtin_bit_cast(float, u);
}
DI f32x4 mfma16(bf16x8 a, bf16x8 b, f32x4 c) {
  return __builtin_amdgcn_mfma_f32_16x16x32_bf16(a, b, c, 0, 0, 0);
}

// Problem constants: B=16 T=12 N=512 D=96 G=4 S=10 K_T=3
// hTt layout: [b][s][d][m] with m = k*512+n   (160*96*1536 bf16)
// cat layout: [b][s][n][c], c in [0,480)      (81920*480 bf16)

// ---------------- K1: h = relu(Xw @ Wu^T), write hTt transposed -------------
// grid 3840 = 160(b,s) * 8(n-tile 64) * 3(k). block 256 (4 waves).
__global__ __launch_bounds__(256) void k1(const float* __restrict__ X,
                                          const float* __restrict__ Wu,
                                          u16* __restrict__ hTt) {
  __shared__ u16 As[64 * 296];   // Xw tile [n=64][c=288] (+8 pad)
  __shared__ u16 Bs[96 * 296];   // Wu rows [j=96][c=288]
  __shared__ u16 Ts[64 * 100];   // transpose buffer [n][d]
  const int wg = blockIdx.x;
  const int kk = wg % 3;
  const int n0 = ((wg / 3) & 7) * 64;
  const int bs = wg / 24;
  const int b = bs / 10, s = bs % 10;
  const int tid = threadIdx.x;

  // stage A: Xw[n0+r][q*4..] = X[b, s+kq, n0+r, dq*4..]
#pragma unroll
  for (int i = 0; i < 18; ++i) {
    int idx = tid + i * 256;          // < 4608 = 64*72
    int r = idx / 72, q = idx % 72;
    int kq = q / 24, dq = q % 24;
    const float4 v = *reinterpret_cast<const float4*>(
        &X[(((b * 12) + s + kq) * 512 + (n0 + r)) * 96 + dq * 4]);
    ushort4 u; u.x = f2bf(v.x); u.y = f2bf(v.y); u.z = f2bf(v.z); u.w = f2bf(v.w);
    *reinterpret_cast<ushort4*>(&As[r * 296 + q * 4]) = u;
  }
  // stage B: Wu rows j_global = kk*96 + j
#pragma unroll
  for (int i = 0; i < 27; ++i) {
    int idx = tid + i * 256;          // < 6912 = 96*72
    int j = idx / 72, q = idx % 72;
    const float4 v = *reinterpret_cast<const float4*>(
        &Wu[(kk * 96 + j) * 288 + q * 4]);
    ushort4 u; u.x = f2bf(v.x); u.y = f2bf(v.y); u.z = f2bf(v.z); u.w = f2bf(v.w);
    *reinterpret_cast<ushort4*>(&Bs[j * 296 + q * 4]) = u;
  }
  __syncthreads();

  const int w = tid >> 6, l = tid & 63;
  const int lr = l & 15, lk = (l >> 4) * 8;
  f32x4 acc[6] = {};
#pragma unroll
  for (int ks = 0; ks < 9; ++ks) {
    bf16x8 a = *reinterpret_cast<const bf16x8*>(&As[(w * 16 + lr) * 296 + ks * 32 + lk]);
#pragma unroll
    for (int ct = 0; ct < 6; ++ct) {
      bf16x8 bb = *reinterpret_cast<const bf16x8*>(&Bs[(ct * 16 + lr) * 296 + ks * 32 + lk]);
      acc[ct] = mfma16(a, bb, acc[ct]);
    }
  }
  // relu, drop into transpose buffer [n][d]
  const int rowb = w * 16 + (l >> 4) * 4;
#pragma unroll
  for (int ct = 0; ct < 6; ++ct) {
#pragma unroll
    for (int rg = 0; rg < 4; ++rg) {
      float v = acc[ct][rg];
      v = v > 0.f ? v : 0.f;
      Ts[(rowb + rg) * 100 + ct * 16 + lr] = f2bf(v);
    }
  }
  __syncthreads();
  // write hTt[bs][d][kk*512 + n0 + n], coalesced along n
  const int obase = bs * 96 * 1536 + kk * 512 + n0;
#pragma unroll
  for (int i = 0; i < 24; ++i) {
    int idx = tid + i * 256;          // < 6144 = 96*64
    int d = idx >> 6, n = idx & 63;
    hTt[obase + d * 1536 + n] = Ts[n * 100 + d];
  }
}

// ---------------- K1b: X0 = mean_k h -> cat[...,0:96] ----------------------
// grid 640 = 160(b,s) * 4(n-chunk 128). block 256.
__global__ __launch_bounds__(256) void k1b(const u16* __restrict__ hTt,
                                           u16* __restrict__ cat) {
  __shared__ u16 Ss[128 * 100];  // [n][d]
  const int wg = blockIdx.x;
  const int nc = (wg & 3) * 128;
  const int bs = wg >> 2;
  const int tid = threadIdx.x;
#pragma unroll
  for (int j = 0; j < 6; ++j) {
    int o = tid + j * 256;            // < 1536 = 96*16
    int d = o >> 4, oc = o & 15;      // oc: which 8-wide n-group
    float a8[8] = {0.f, 0.f, 0.f, 0.f, 0.f, 0.f, 0.f, 0.f};
#pragma unroll
    for (int k = 0; k < 3; ++k) {
      const uint4 v = *reinterpret_cast<const uint4*>(
          &hTt[(bs * 96 + d) * 1536 + k * 512 + nc + oc * 8]);
      a8[0] += bf2f((u16)(v.x & 0xffffu)); a8[1] += bf2f((u16)(v.x >> 16));
      a8[2] += bf2f((u16)(v.y & 0xffffu)); a8[3] += bf2f((u16)(v.y >> 16));
      a8[4] += bf2f((u16)(v.z & 0xffffu)); a8[5] += bf2f((u16)(v.z >> 16));
      a8[6] += bf2f((u16)(v.w & 0xffffu)); a8[7] += bf2f((u16)(v.w >> 16));
    }
#pragma unroll
    for (int e = 0; e < 8; ++e)
      Ss[(oc * 8 + e) * 100 + d] = f2bf(a8[e] * (1.f / 3.f));
  }
  __syncthreads();
  const long ob = ((long)bs * 512 + nc) * 480;
#pragma unroll
  for (int i = 0; i < 48; ++i) {
    int idx = tid + i * 256;          // < 12288 = 128*96
    int n = idx / 96, d = idx % 96;
    cat[ob + n * 480 + d] = Ss[n * 100 + d];
  }
}

// ---------------- K2: Hk einsum -> cat[..., 96:480] ------------------------
// Per b: Out[(g,n),(s,d)] = sum_m dyn[g,b,n,m] * hTt[b,s,d,m]
// grid 1280 = 16(b) * 16(row-tile: g, n0 128) * 5(s-pair). block 256 (4 waves).
__global__ __launch_bounds__(256) void k2(const float* __restrict__ dyn,
                                          const u16* __restrict__ hTt,
                                          u16* __restrict__ cat) {
  __shared__ u16 As[128 * 72];   // dyn tile  [n=128][m=64] (+8 pad)
  __shared__ u16 Bs[192 * 72];   // hTt tile  [c=(sl,d)=192][m=64]
  const int wg = blockIdx.x;
  const int sp = wg % 5, rt = (wg / 5) & 15, b = wg / 80;
  const int g = rt >> 2, n0 = (rt & 3) * 128, s0 = sp * 2;
  const int tid = threadIdx.x;
  const int w = tid >> 6, l = tid & 63;
  const int lr = l & 15, lk = (l >> 4) * 8;
  f32x4 acc[2][12] = {};
  const int abase = ((g * 16 + b) * 512 + n0) * 1536;
  const int bbase = (b * 10 + s0) * 96 * 1536;

  for (int m0 = 0; m0 < 1536; m0 += 64) {
#pragma unroll
    for (int i = 0; i < 8; ++i) {
      int idx = tid + i * 256;        // < 2048 = 128*16
      int r = idx >> 4, q = idx & 15;
      const float4 v = *reinterpret_cast<const float4*>(
          &dyn[abase + r * 1536 + m0 + q * 4]);
      ushort4 u; u.x = f2bf(v.x); u.y = f2bf(v.y); u.z = f2bf(v.z); u.w = f2bf(v.w);
      *reinterpret_cast<ushort4*>(&As[r * 72 + q * 4]) = u;
    }
#pragma unroll
    for (int i = 0; i < 12; ++i) {
      int idx = tid + i * 256;        // < 3072 = 192*16
      int c = idx >> 4, q = idx & 15;
      const ushort4 v = *reinterpret_cast<const ushort4*>(
          &hTt[bbase + c * 1536 + m0 + q * 4]);
      *reinterpret_cast<ushort4*>(&Bs[c * 72 + q * 4]) = v;
    }
    __syncthreads();
#pragma unroll
    for (int ks = 0; ks < 2; ++ks) {
      bf16x8 a0 = *reinterpret_cast<const bf16x8*>(&As[(w * 32 + lr) * 72 + ks * 32 + lk]);
      bf16x8 a1 = *reinterpret_cast<const bf16x8*>(&As[(w * 32 + 16 + lr) * 72 + ks * 32 + lk]);
#pragma unroll
      for (int ct = 0; ct < 12; ++ct) {
        bf16x8 bb = *reinterpret_cast<const bf16x8*>(&Bs[(ct * 16 + lr) * 72 + ks * 32 + lk]);
        acc[0][ct] = mfma16(a0, bb, acc[0][ct]);
        acc[1][ct] = mfma16(a1, bb, acc[1][ct]);
      }
    }
    __syncthreads();
  }
  // epilogue: cat[b, s0+sl, n, 96 + g*96 + d]
#pragma unroll
  for (int rt2 = 0; rt2 < 2; ++rt2) {
    const int nrow = n0 + w * 32 + rt2 * 16 + (l >> 4) * 4;
#pragma unroll
    for (int ct = 0; ct < 12; ++ct) {
      const int sl = ct / 6;
      const int d = ct * 16 + lr - sl * 96;
      const long ob = (long)((b * 10 + s0 + sl) * 512) * 480;
#pragma unroll
      for (int rg = 0; rg < 4; ++rg)
        cat[ob + (long)(nrow + rg) * 480 + 96 + g * 96 + d] = f2bf(acc[rt2][ct][rg]);
    }
  }
}

// ---------------- K3: out = cat @ Wg^T + bias -------------------------------
// grid 640 (row-tiles of 128 over 81920 rows). block 256 (4 waves).
__global__ __launch_bounds__(256) void k3(const u16* __restrict__ cat,
                                          const float* __restrict__ Wg,
                                          const float* __restrict__ bias,
                                          float* __restrict__ out) {
  __shared__ u16 As[128 * 104];  // cat tile [r=128][c=96] (+8 pad)
  __shared__ u16 Bs[96 * 104];   // Wg rows  [do=96][c=96]
  const int row0 = blockIdx.x * 128;
  const int tid = threadIdx.x;
  const int w = tid >> 6, l = tid & 63;
  const int lr = l & 15, lk = (l >> 4) * 8;
  f32x4 acc[2][6] = {};

  for (int c0 = 0; c0 < 480; c0 += 96) {
#pragma unroll
    for (int i = 0; i < 12; ++i) {
      int idx = tid + i * 256;        // < 3072 = 128*24
      int r = idx / 24, q = idx % 24;
      const ushort4 v = *reinterpret_cast<const ushort4*>(
          &cat[(long)(row0 + r) * 480 + c0 + q * 4]);
      *reinterpret_cast<ushort4*>(&As[r * 104 + q * 4]) = v;
    }
#pragma unroll
    for (int i = 0; i < 9; ++i) {
      int idx = tid + i * 256;        // < 2304 = 96*24
      int j = idx / 24, q = idx % 24;
      const float4 v = *reinterpret_cast<const float4*>(&Wg[j * 480 + c0 + q * 4]);
      ushort4 u; u.x = f2bf(v.x); u.y = f2bf(v.y); u.z = f2bf(v.z); u.w = f2bf(v.w);
      *reinterpret_cast<ushort4*>(&Bs[j * 104 + q * 4]) = u;
    }
    __syncthreads();
#pragma unroll
    for (int ks = 0; ks < 3; ++ks) {
      bf16x8 a0 = *reinterpret_cast<const bf16x8*>(&As[(w * 32 + lr) * 104 + ks * 32 + lk]);
      bf16x8 a1 = *reinterpret_cast<const bf16x8*>(&As[(w * 32 + 16 + lr) * 104 + ks * 32 + lk]);
#pragma unroll
      for (int ct = 0; ct < 6; ++ct) {
        bf16x8 bb = *reinterpret_cast<const bf16x8*>(&Bs[(ct * 16 + lr) * 104 + ks * 32 + lk]);
        acc[0][ct] = mfma16(a0, bb, acc[0][ct]);
        acc[1][ct] = mfma16(a1, bb, acc[1][ct]);
      }
    }
    __syncthreads();
  }
#pragma unroll
  for (int rt2 = 0; rt2 < 2; ++rt2) {
    const int r = row0 + w * 32 + rt2 * 16 + (l >> 4) * 4;
#pragma unroll
    for (int ct = 0; ct < 6; ++ct) {
      const int dd = ct * 16 + lr;
      const float bv = bias[dd];
#pragma unroll
      for (int rg = 0; rg < 4; ++rg)
        out[(long)(r + rg) * 96 + dd] = acc[rt2][ct][rg] + bv;
    }
  }
}

extern "C" void kernel_launch(void* const* d_in, const int* in_sizes, int n_in,
                              void* d_out, int out_size, void* d_ws, size_t ws_size,
                              hipStream_t stream) {
  const float* X    = (const float*)d_in[0];
  const float* dyn  = (const float*)d_in[1];
  const float* Wu   = (const float*)d_in[2];
  const float* Wg   = (const float*)d_in[3];
  const float* bias = (const float*)d_in[4];
  float* out = (float*)d_out;

  const size_t hTt_elems = (size_t)160 * 96 * 1536;   // 23,592,960
  const size_t cat_elems = (size_t)81920 * 480;       // 39,321,600
  if (ws_size < (hTt_elems + cat_elems) * sizeof(u16)) return;  // fail loudly
  u16* hTt = (u16*)d_ws;
  u16* cat = hTt + hTt_elems;

  hipLaunchKernelGGL(k1,  dim3(3840), dim3(256), 0, stream, X, Wu, hTt);
  hipLaunchKernelGGL(k1b, dim3(640),  dim3(256), 0, stream, hTt, cat);
  hipLaunchKernelGGL(k2,  dim3(1280), dim3(256), 0, stream, dyn, hTt, cat);
  hipLaunchKernelGGL(k3,  dim3(640),  dim3(256), 0, stream, cat, Wg, bias, out);
}

// Round 2
// 301.065 us; speedup vs baseline: 2.5416x; 2.5416x over previous
//
#include <hip/hip_runtime.h>

typedef unsigned short u16;
typedef unsigned int u32;
typedef __attribute__((ext_vector_type(4))) float f32x4;
typedef __bf16 bf16x8 __attribute__((ext_vector_type(8)));

#define DI __device__ __forceinline__

DI u16 f2bf(float f) {
  unsigned u = __builtin_bit_cast(unsigned, f);
  u += 0x7fffu + ((u >> 16) & 1u);
  return (u16)(u >> 16);
}
DI float bf2f(u16 h) {
  unsigned u = ((unsigned)h) << 16;
  return __builtin_bit_cast(float, u);
}
DI f32x4 mfma16(bf16x8 a, bf16x8 b, f32x4 c) {
  return __builtin_amdgcn_mfma_f32_16x16x32_bf16(a, b, c, 0, 0, 0);
}
DI void gload_lds16(const void* g, void* l) {
  __builtin_amdgcn_global_load_lds(
      (const __attribute__((address_space(1))) u32*)g,
      (__attribute__((address_space(3))) u32*)l, 16, 0, 0);
}

// Problem constants: B=16 T=12 N=512 D=96 G=4 S=10 K_T=3
// hTt layout: [b][s][d][m] with m = k*512+n   (160*96*1536 bf16)
// cat layout: [b][s][n][c], c in [0,480)      (81920*480 bf16)

// ---------------- K1: h = relu(Xw @ Wu^T), write hTt transposed -------------
// grid 3840 = 160(b,s) * 8(n-tile 64) * 3(k). block 256 (4 waves).
__global__ __launch_bounds__(256) void k1(const float* __restrict__ X,
                                          const float* __restrict__ Wu,
                                          u16* __restrict__ hTt) {
  __shared__ u16 As[64 * 296];   // Xw tile [n=64][c=288] (+8 pad)
  __shared__ u16 Bs[96 * 296];   // Wu rows [j=96][c=288]
  __shared__ u16 Ts[64 * 100];   // transpose buffer [n][d]
  const int wg = blockIdx.x;
  const int kk = wg % 3;
  const int n0 = ((wg / 3) & 7) * 64;
  const int bs = wg / 24;
  const int b = bs / 10, s = bs % 10;
  const int tid = threadIdx.x;

#pragma unroll
  for (int i = 0; i < 18; ++i) {
    int idx = tid + i * 256;          // < 4608 = 64*72
    int r = idx / 72, q = idx % 72;
    int kq = q / 24, dq = q % 24;
    const float4 v = *reinterpret_cast<const float4*>(
        &X[(((b * 12) + s + kq) * 512 + (n0 + r)) * 96 + dq * 4]);
    ushort4 u; u.x = f2bf(v.x); u.y = f2bf(v.y); u.z = f2bf(v.z); u.w = f2bf(v.w);
    *reinterpret_cast<ushort4*>(&As[r * 296 + q * 4]) = u;
  }
#pragma unroll
  for (int i = 0; i < 27; ++i) {
    int idx = tid + i * 256;          // < 6912 = 96*72
    int j = idx / 72, q = idx % 72;
    const float4 v = *reinterpret_cast<const float4*>(
        &Wu[(kk * 96 + j) * 288 + q * 4]);
    ushort4 u; u.x = f2bf(v.x); u.y = f2bf(v.y); u.z = f2bf(v.z); u.w = f2bf(v.w);
    *reinterpret_cast<ushort4*>(&Bs[j * 296 + q * 4]) = u;
  }
  __syncthreads();

  const int w = tid >> 6, l = tid & 63;
  const int lr = l & 15, lk = (l >> 4) * 8;
  f32x4 acc[6] = {};
#pragma unroll
  for (int ks = 0; ks < 9; ++ks) {
    bf16x8 a = *reinterpret_cast<const bf16x8*>(&As[(w * 16 + lr) * 296 + ks * 32 + lk]);
#pragma unroll
    for (int ct = 0; ct < 6; ++ct) {
      bf16x8 bb = *reinterpret_cast<const bf16x8*>(&Bs[(ct * 16 + lr) * 296 + ks * 32 + lk]);
      acc[ct] = mfma16(a, bb, acc[ct]);
    }
  }
  const int rowb = w * 16 + (l >> 4) * 4;
#pragma unroll
  for (int ct = 0; ct < 6; ++ct) {
#pragma unroll
    for (int rg = 0; rg < 4; ++rg) {
      float v = acc[ct][rg];
      v = v > 0.f ? v : 0.f;
      Ts[(rowb + rg) * 100 + ct * 16 + lr] = f2bf(v);
    }
  }
  __syncthreads();
  const int obase = bs * 96 * 1536 + kk * 512 + n0;
#pragma unroll
  for (int i = 0; i < 24; ++i) {
    int idx = tid + i * 256;          // < 6144 = 96*64
    int d = idx >> 6, n = idx & 63;
    hTt[obase + d * 1536 + n] = Ts[n * 100 + d];
  }
}

// ---------------- K1b: X0 = mean_k h -> cat[...,0:96] ----------------------
__global__ __launch_bounds__(256) void k1b(const u16* __restrict__ hTt,
                                           u16* __restrict__ cat) {
  __shared__ u16 Ss[128 * 100];  // [n][d]
  const int wg = blockIdx.x;
  const int nc = (wg & 3) * 128;
  const int bs = wg >> 2;
  const int tid = threadIdx.x;
#pragma unroll
  for (int j = 0; j < 6; ++j) {
    int o = tid + j * 256;            // < 1536 = 96*16
    int d = o >> 4, oc = o & 15;
    float a8[8] = {0.f, 0.f, 0.f, 0.f, 0.f, 0.f, 0.f, 0.f};
#pragma unroll
    for (int k = 0; k < 3; ++k) {
      const uint4 v = *reinterpret_cast<const uint4*>(
          &hTt[(bs * 96 + d) * 1536 + k * 512 + nc + oc * 8]);
      a8[0] += bf2f((u16)(v.x & 0xffffu)); a8[1] += bf2f((u16)(v.x >> 16));
      a8[2] += bf2f((u16)(v.y & 0xffffu)); a8[3] += bf2f((u16)(v.y >> 16));
      a8[4] += bf2f((u16)(v.z & 0xffffu)); a8[5] += bf2f((u16)(v.z >> 16));
      a8[6] += bf2f((u16)(v.w & 0xffffu)); a8[7] += bf2f((u16)(v.w >> 16));
    }
#pragma unroll
    for (int e = 0; e < 8; ++e)
      Ss[(oc * 8 + e) * 100 + d] = f2bf(a8[e] * (1.f / 3.f));
  }
  __syncthreads();
  const long ob = ((long)bs * 512 + nc) * 480;
#pragma unroll
  for (int i = 0; i < 48; ++i) {
    int idx = tid + i * 256;          // < 12288 = 128*96
    int n = idx / 96, d = idx % 96;
    cat[ob + n * 480 + d] = Ss[n * 100 + d];
  }
}

// ---------------- K2: Hk einsum -> cat[..., 96:480] ------------------------
// Per b: Out[(g,n),(s,d)] = sum_m dyn[g,b,n,m] * hTt[b,s,d,m]
// 2-phase pipelined, double-buffered LDS, gloadlds for B, reg-staged A.
// grid 1280 = 16(b)*16(g,n0)*5(sp). block 512 (8 waves: 4 wm x 2 wn).
// Wave tile 32(n) x 96(s,d). LDS swizzle: elem ^ ((row&7)<<3).
__global__ __launch_bounds__(512, 4) void k2(const float* __restrict__ dyn,
                                             const u16* __restrict__ hTt,
                                             u16* __restrict__ cat) {
  __shared__ u16 As[2][128 * 64];   // dyn tile  [n=128][m=64] bf16, swizzled
  __shared__ u16 Bs[2][192 * 64];   // hTt tile  [c=(sl,d)=192][m=64], swizzled
  const int wg0 = blockIdx.x;
  const int wg = (wg0 & 7) * 160 + (wg0 >> 3);   // bijective XCD swizzle
  const int sp = wg % 5, rt = (wg / 5) & 15, b = wg / 80;
  const int g = rt >> 2, n0 = (rt & 3) * 128, s0 = sp * 2;
  const int tid = threadIdx.x;
  const int w = tid >> 6, l = tid & 63;
  const int wm = w & 3, wn = w >> 2;
  const int lr = l & 15, q = l >> 4;
  const int sw = (lr & 7) << 3;
  const long abase = (long)((g * 16 + b) * 512 + n0) * 1536;
  const int bbase = (b * 10 + s0) * 96 * 1536;

  // A staging: thread t covers row ar_s (0..127), 16-float segment qs (0..3)
  const int ar_s = tid >> 2, qs = tid & 3;
  const float* aptr = &dyn[abase + (long)ar_s * 1536 + qs * 16];
  const int awo0 = ar_s * 64 + ((qs * 16) ^ ((ar_s & 7) << 3));
  const int awo1 = ar_s * 64 + ((qs * 16 + 8) ^ ((ar_s & 7) << 3));

  // B staging: 3 gloadlds issues; row c = j*64 + (tid>>3); pre-swizzled source
  const int brow = tid >> 3;
  const int bsrc_sw = ((tid & 7) ^ (brow & 7)) * 8;

  f32x4 acc[2][6] = {};
  float4 ld0, ld1, ld2, ld3;

  auto stageA_load = [&](int t) {
    const float* p = aptr + t * 64;
    ld0 = *reinterpret_cast<const float4*>(p);
    ld1 = *reinterpret_cast<const float4*>(p + 4);
    ld2 = *reinterpret_cast<const float4*>(p + 8);
    ld3 = *reinterpret_cast<const float4*>(p + 12);
  };
  auto issueB = [&](int t, int buf) {
#pragma unroll
    for (int j = 0; j < 3; ++j) {
      const u16* src = &hTt[bbase + (j * 64 + brow) * 1536 + t * 64 + bsrc_sw];
      u16* dst = &Bs[buf][j * 4096 + w * 512];   // wave-uniform base
      gload_lds16(src, dst);
    }
  };
  auto stageA_write = [&](int buf) {
    u32 pk[8];
    pk[0] = ((u32)f2bf(ld0.y) << 16) | f2bf(ld0.x);
    pk[1] = ((u32)f2bf(ld0.w) << 16) | f2bf(ld0.z);
    pk[2] = ((u32)f2bf(ld1.y) << 16) | f2bf(ld1.x);
    pk[3] = ((u32)f2bf(ld1.w) << 16) | f2bf(ld1.z);
    pk[4] = ((u32)f2bf(ld2.y) << 16) | f2bf(ld2.x);
    pk[5] = ((u32)f2bf(ld2.w) << 16) | f2bf(ld2.z);
    pk[6] = ((u32)f2bf(ld3.y) << 16) | f2bf(ld3.x);
    pk[7] = ((u32)f2bf(ld3.w) << 16) | f2bf(ld3.z);
    uint4 v0; v0.x = pk[0]; v0.y = pk[1]; v0.z = pk[2]; v0.w = pk[3];
    uint4 v1; v1.x = pk[4]; v1.y = pk[5]; v1.z = pk[6]; v1.w = pk[7];
    *reinterpret_cast<uint4*>(&As[buf][awo0]) = v0;
    *reinterpret_cast<uint4*>(&As[buf][awo1]) = v1;
  };
  auto compute = [&](int buf) {
#pragma unroll
    for (int ks = 0; ks < 2; ++ks) {
      const int ko = (ks * 32 + q * 8) ^ sw;
      bf16x8 a0 = *reinterpret_cast<const bf16x8*>(&As[buf][(wm * 32 + lr) * 64 + ko]);
      bf16x8 a1 = *reinterpret_cast<const bf16x8*>(&As[buf][(wm * 32 + 16 + lr) * 64 + ko]);
#pragma unroll
      for (int ct = 0; ct < 6; ++ct) {
        bf16x8 bb = *reinterpret_cast<const bf16x8*>(&Bs[buf][(wn * 96 + ct * 16 + lr) * 64 + ko]);
        acc[0][ct] = mfma16(a0, bb, acc[0][ct]);
        acc[1][ct] = mfma16(a1, bb, acc[1][ct]);
      }
    }
  };

  // prologue: stage tile 0 into buf 0
  stageA_load(0);
  issueB(0, 0);
  stageA_write(0);
  __syncthreads();
  int p = 0;
  for (int t = 0; t < 24; ++t) {
    if (t < 23) {
      stageA_load(t + 1);      // issue global loads early (overlap MFMA)
      issueB(t + 1, p ^ 1);    // async direct-to-LDS, stays in flight
    }
    compute(p);
    if (t < 23) stageA_write(p ^ 1);   // waits vmcnt for A regs only
    __syncthreads();
    p ^= 1;
  }

  // epilogue: cat[b, s0+wn, n0+wm*32+row, 96 + g*96 + d]
  const long cb = (long)((b * 10 + s0 + wn) * 512 + n0 + wm * 32) * 480 + 96 + g * 96;
#pragma unroll
  for (int rt2 = 0; rt2 < 2; ++rt2) {
#pragma unroll
    for (int ct = 0; ct < 6; ++ct) {
      const int d = ct * 16 + lr;
#pragma unroll
      for (int rg = 0; rg < 4; ++rg) {
        const int row = rt2 * 16 + q * 4 + rg;
        cat[cb + (long)row * 480 + d] = f2bf(acc[rt2][ct][rg]);
      }
    }
  }
}

// ---------------- K3: out = cat @ Wg^T + bias -------------------------------
__global__ __launch_bounds__(256) void k3(const u16* __restrict__ cat,
                                          const float* __restrict__ Wg,
                                          const float* __restrict__ bias,
                                          float* __restrict__ out) {
  __shared__ u16 As[128 * 104];  // cat tile [r=128][c=96] (+8 pad)
  __shared__ u16 Bs[96 * 104];   // Wg rows  [do=96][c=96]
  const int row0 = blockIdx.x * 128;
  const int tid = threadIdx.x;
  const int w = tid >> 6, l = tid & 63;
  const int lr = l & 15, lk = (l >> 4) * 8;
  f32x4 acc[2][6] = {};

  for (int c0 = 0; c0 < 480; c0 += 96) {
#pragma unroll
    for (int i = 0; i < 12; ++i) {
      int idx = tid + i * 256;        // < 3072 = 128*24
      int r = idx / 24, q = idx % 24;
      const ushort4 v = *reinterpret_cast<const ushort4*>(
          &cat[(long)(row0 + r) * 480 + c0 + q * 4]);
      *reinterpret_cast<ushort4*>(&As[r * 104 + q * 4]) = v;
    }
#pragma unroll
    for (int i = 0; i < 9; ++i) {
      int idx = tid + i * 256;        // < 2304 = 96*24
      int j = idx / 24, q = idx % 24;
      const float4 v = *reinterpret_cast<const float4*>(&Wg[j * 480 + c0 + q * 4]);
      ushort4 u; u.x = f2bf(v.x); u.y = f2bf(v.y); u.z = f2bf(v.z); u.w = f2bf(v.w);
      *reinterpret_cast<ushort4*>(&Bs[j * 104 + q * 4]) = u;
    }
    __syncthreads();
#pragma unroll
    for (int ks = 0; ks < 3; ++ks) {
      bf16x8 a0 = *reinterpret_cast<const bf16x8*>(&As[(w * 32 + lr) * 104 + ks * 32 + lk]);
      bf16x8 a1 = *reinterpret_cast<const bf16x8*>(&As[(w * 32 + 16 + lr) * 104 + ks * 32 + lk]);
#pragma unroll
      for (int ct = 0; ct < 6; ++ct) {
        bf16x8 bb = *reinterpret_cast<const bf16x8*>(&Bs[(ct * 16 + lr) * 104 + ks * 32 + lk]);
        acc[0][ct] = mfma16(a0, bb, acc[0][ct]);
        acc[1][ct] = mfma16(a1, bb, acc[1][ct]);
      }
    }
    __syncthreads();
  }
#pragma unroll
  for (int rt2 = 0; rt2 < 2; ++rt2) {
    const int r = row0 + w * 32 + rt2 * 16 + (l >> 4) * 4;
#pragma unroll
    for (int ct = 0; ct < 6; ++ct) {
      const int dd = ct * 16 + lr;
      const float bv = bias[dd];
#pragma unroll
      for (int rg = 0; rg < 4; ++rg)
        out[(long)(r + rg) * 96 + dd] = acc[rt2][ct][rg] + bv;
    }
  }
}

extern "C" void kernel_launch(void* const* d_in, const int* in_sizes, int n_in,
                              void* d_out, int out_size, void* d_ws, size_t ws_size,
                              hipStream_t stream) {
  const float* X    = (const float*)d_in[0];
  const float* dyn  = (const float*)d_in[1];
  const float* Wu   = (const float*)d_in[2];
  const float* Wg   = (const float*)d_in[3];
  const float* bias = (const float*)d_in[4];
  float* out = (float*)d_out;

  const size_t hTt_elems = (size_t)160 * 96 * 1536;   // 23,592,960
  const size_t cat_elems = (size_t)81920 * 480;       // 39,321,600
  if (ws_size < (hTt_elems + cat_elems) * sizeof(u16)) return;
  u16* hTt = (u16*)d_ws;
  u16* cat = hTt + hTt_elems;

  hipLaunchKernelGGL(k1,  dim3(3840), dim3(256), 0, stream, X, Wu, hTt);
  hipLaunchKernelGGL(k1b, dim3(640),  dim3(256), 0, stream, hTt, cat);
  hipLaunchKernelGGL(k2,  dim3(1280), dim3(512), 0, stream, dyn, hTt, cat);
  hipLaunchKernelGGL(k3,  dim3(640),  dim3(256), 0, stream, cat, Wg, bias, out);
}